// Round 1
// baseline (386.302 us; speedup 1.0000x reference)
//
#include <hip/hip_runtime.h>

typedef __attribute__((ext_vector_type(8))) short bf16x8;
typedef __attribute__((ext_vector_type(4))) float f32x4;
typedef __attribute__((ext_vector_type(2))) float f32x2;

#define BB 1024
#define TT 256
#define DD 63
#define HH 128
#define G4 512
#define CHUNK 4
#define HSTR 136   // hbuf row stride in shorts (128 + 8 pad -> 2-way-conflict-free b128 reads)
#define XSTR 72    // xbuf row stride in shorts (64 + 8 pad)

__device__ __forceinline__ short f2bf(float f) {
  unsigned u = __builtin_bit_cast(unsigned, f);
  u = (u + 0x7FFFu + ((u >> 16) & 1u)) >> 16;   // RNE
  return (short)u;
}
__device__ __forceinline__ float sigm(float x) {
  return __builtin_amdgcn_rcpf(1.f + __expf(-x));   // handles +-inf correctly
}
__device__ __forceinline__ float tanh_fast(float x) {
  float e = __expf(2.f * x);
  return 1.f - 2.f * __builtin_amdgcn_rcpf(e + 1.f); // saturates correctly at +-1
}

// Forward-direction LSTM over all T, chunk of 4 batch rows per workgroup.
// Epilogue writes the forward half of the FC output (no bias) into d_out.
__global__ __launch_bounds__(256, 1)
void lstm_fwd_kernel(const float* __restrict__ X,
                     const float* __restrict__ Wih,
                     const float* __restrict__ Whh,
                     const float* __restrict__ bih,
                     const float* __restrict__ bhh,
                     const float* __restrict__ Wfc,
                     float* __restrict__ out) {
  __shared__ __align__(16) short hbuf[16 * HSTR];        // h (bf16), rows 0..3 valid
  __shared__ __align__(16) short xbuf[2 * 16 * XSTR];    // x_t (bf16), double buffered
  __shared__ __align__(16) float glds[G4 * 4];           // gates [col n][row r]

  const int tid  = threadIdx.x;
  const int wave = tid >> 6;
  const int lane = tid & 63;
  const int quad = lane >> 4;
  const int l15  = lane & 15;
  const int b0   = blockIdx.x * CHUNK;

  // ---- register-resident W fragments (one-time, L2/L3-cached across wgs) ----
  bf16x8 Bh[8][4];   // W_hh B-frags: tile, kstep(32)
  bf16x8 Bx[8][2];   // W_ih B-frags: tile, kstep(32), K padded 63->64
  {
    const int n_base = wave * 128 + l15;
#pragma unroll
    for (int tile = 0; tile < 8; ++tile) {
      const int n = n_base + tile * 16;
      const float* wr = Whh + (size_t)n * HH;
#pragma unroll
      for (int ks = 0; ks < 4; ++ks) {
        const int k0 = ks * 32 + quad * 8;
        bf16x8 v;
#pragma unroll
        for (int j = 0; j < 8; ++j) v[j] = f2bf(wr[k0 + j]);
        Bh[tile][ks] = v;
      }
      const float* xr = Wih + (size_t)n * DD;
#pragma unroll
      for (int ks = 0; ks < 2; ++ks) {
        const int k0 = ks * 32 + quad * 8;
        bf16x8 v;
#pragma unroll
        for (int j = 0; j < 8; ++j) {
          const int k = k0 + j;
          v[j] = (k < DD) ? f2bf(xr[k]) : (short)0;
        }
        Bx[tile][ks] = v;
      }
    }
  }

  // elementwise thread mapping: col j of each gate, row pair rp
  const int j  = tid & 127;
  const int rp = tid >> 7;          // rows rp*2, rp*2+1
  float bg[4];
#pragma unroll
  for (int g = 0; g < 4; ++g) bg[g] = bih[g * HH + j] + bhh[g * HH + j];

  for (int i = tid; i < 16 * HSTR; i += 256) hbuf[i] = 0;

  // x prefetch mapping: 4 rows x 63 cols = 252 threads
  const int xrow = tid / DD;
  const int xd   = tid - xrow * DD;
  const bool xthr = (tid < CHUNK * DD);
  const float* xbase = X + ((size_t)(b0 + xrow) * TT) * DD + xd;
  if (xthr) xbuf[xrow * XSTR + xd] = f2bf(xbase[0]);
  __syncthreads();

  float c0 = 0.f, c1 = 0.f, h0v = 0.f, h1v = 0.f;
  const f32x4 zero4 = {0.f, 0.f, 0.f, 0.f};

  for (int t = 0; t < TT; ++t) {
    const int cur = (t & 1) * (16 * XSTR);

    // A-fragments (same for all waves): h rows + x rows
    bf16x8 Ah[4], Ax[2];
#pragma unroll
    for (int ks = 0; ks < 4; ++ks)
      Ah[ks] = *(const bf16x8*)&hbuf[l15 * HSTR + ks * 32 + quad * 8];
#pragma unroll
    for (int ks = 0; ks < 2; ++ks)
      Ax[ks] = *(const bf16x8*)&xbuf[cur + l15 * XSTR + ks * 32 + quad * 8];

    // prefetch next timestep's x (latency hidden behind MFMA + elementwise)
    float xv = 0.f;
    const bool pf = xthr && (t + 1 < TT);
    if (pf) xv = xbase[(size_t)(t + 1) * DD];

    // ---- MFMA: gates = h @ Whh^T + x @ Wih^T  (bias added later) ----
    f32x4 acc[8];
#pragma unroll
    for (int tile = 0; tile < 8; ++tile)
      acc[tile] = __builtin_amdgcn_mfma_f32_16x16x32_bf16(Ah[0], Bh[tile][0], zero4, 0, 0, 0);
#pragma unroll
    for (int ks = 1; ks < 4; ++ks)
#pragma unroll
      for (int tile = 0; tile < 8; ++tile)
        acc[tile] = __builtin_amdgcn_mfma_f32_16x16x32_bf16(Ah[ks], Bh[tile][ks], acc[tile], 0, 0, 0);
#pragma unroll
    for (int ks = 0; ks < 2; ++ks)
#pragma unroll
      for (int tile = 0; tile < 8; ++tile)
        acc[tile] = __builtin_amdgcn_mfma_f32_16x16x32_bf16(Ax[ks], Bx[tile][ks], acc[tile], 0, 0, 0);

    // valid rows 0..3 live in quad 0; write [col][row] so 4 rows = one b128
    if (quad == 0) {
#pragma unroll
      for (int tile = 0; tile < 8; ++tile) {
        const int n = wave * 128 + tile * 16 + l15;
        *(f32x4*)&glds[n * 4] = acc[tile];
      }
    }
    __syncthreads();

    // ---- elementwise: 2 c-elements per thread ----
    f32x2 gi = *(const f32x2*)&glds[(0 * HH + j) * 4 + rp * 2];
    f32x2 gf = *(const f32x2*)&glds[(1 * HH + j) * 4 + rp * 2];
    f32x2 gg = *(const f32x2*)&glds[(2 * HH + j) * 4 + rp * 2];
    f32x2 go = *(const f32x2*)&glds[(3 * HH + j) * 4 + rp * 2];
    {
      float iv = sigm(gi.x + bg[0]);
      float fv = sigm(gf.x + bg[1]);
      float gv = tanh_fast(gg.x + bg[2]);
      float ov = sigm(go.x + bg[3]);
      c0 = fv * c0 + iv * gv;
      h0v = ov * tanh_fast(c0);
      hbuf[(rp * 2 + 0) * HSTR + j] = f2bf(h0v);
    }
    {
      float iv = sigm(gi.y + bg[0]);
      float fv = sigm(gf.y + bg[1]);
      float gv = tanh_fast(gg.y + bg[2]);
      float ov = sigm(go.y + bg[3]);
      c1 = fv * c1 + iv * gv;
      h1v = ov * tanh_fast(c1);
      hbuf[(rp * 2 + 1) * HSTR + j] = f2bf(h1v);
    }

    if (pf) xbuf[(cur ^ (16 * XSTR)) + xrow * XSTR + xd] = f2bf(xv);
    __syncthreads();
  }

  // ---- epilogue: forward half of FC (fp32, no bias) ----
  // reuse glds as h_f staging [4][128]
  glds[(rp * 2 + 0) * HH + j] = h0v;
  glds[(rp * 2 + 1) * HH + j] = h1v;
  __syncthreads();
  if (tid < 4 * 14) {
    const int r = tid / 14, o = tid - r * 14;
    const float* wr = Wfc + (size_t)o * (2 * HH);
    float acc = 0.f;
#pragma unroll 16
    for (int k = 0; k < HH; ++k) acc += wr[k] * glds[r * HH + k];
    out[(size_t)(b0 + r) * 14 + o] = acc;
  }
}

// Backward direction collapses to ONE cell step on x[:,T-1] (h0=c0=0),
// done in exact fp32, plus the backward half of the FC (+ biases).
__global__ __launch_bounds__(256, 2)
void lstm_bwd_fc_kernel(const float* __restrict__ X,
                        const float* __restrict__ Wih_b,
                        const float* __restrict__ bih_b,
                        const float* __restrict__ bhh_b,
                        const float* __restrict__ Wfc,
                        const float* __restrict__ bfc,
                        float* __restrict__ out) {
  __shared__ float xl[DD];
  __shared__ float gl[G4];
  __shared__ float hl[HH];
  __shared__ float pl[14 * 8];
  const int b = blockIdx.x;
  const int tid = threadIdx.x;

  if (tid < DD) xl[tid] = X[((size_t)b * TT + (TT - 1)) * DD + tid];
  __syncthreads();

#pragma unroll
  for (int u = 0; u < 2; ++u) {
    const int n = tid * 2 + u;
    const float* wr = Wih_b + (size_t)n * DD;
    float acc = bih_b[n] + bhh_b[n];
#pragma unroll
    for (int k = 0; k < DD; ++k) acc += wr[k] * xl[k];
    gl[n] = acc;
  }
  __syncthreads();

  if (tid < HH) {
    float iv = sigm(gl[0 * HH + tid]);
    float gv = tanh_fast(gl[2 * HH + tid]);
    float ov = sigm(gl[3 * HH + tid]);
    hl[tid] = ov * tanh_fast(iv * gv);   // c = f*0 + i*g
  }
  __syncthreads();

  if (tid < 14 * 8) {
    const int o = tid >> 3, kp = tid & 7;
    const float* wr = Wfc + (size_t)o * (2 * HH) + HH;
    float acc = 0.f;
#pragma unroll
    for (int i = 0; i < 16; ++i) {
      const int jj = kp * 16 + i;
      acc += wr[jj] * hl[jj];
    }
    pl[tid] = acc;
  }
  __syncthreads();

  if (tid < 14) {
    float acc = bfc[tid];
#pragma unroll
    for (int i = 0; i < 8; ++i) acc += pl[tid * 8 + i];
    out[(size_t)b * 14 + tid] += acc;   // add to forward partial from kernel A
  }
}

extern "C" void kernel_launch(void* const* d_in, const int* in_sizes, int n_in,
                              void* d_out, int out_size, void* d_ws, size_t ws_size,
                              hipStream_t stream) {
  const float* X     = (const float*)d_in[0];
  const float* Wih_f = (const float*)d_in[1];
  const float* Whh_f = (const float*)d_in[2];
  const float* bih_f = (const float*)d_in[3];
  const float* bhh_f = (const float*)d_in[4];
  const float* Wih_b = (const float*)d_in[5];
  // d_in[6] = W_hh_b: unused (backward dir needs only one step from zero state)
  const float* bih_b = (const float*)d_in[7];
  const float* bhh_b = (const float*)d_in[8];
  const float* Wfc   = (const float*)d_in[9];
  const float* bfc   = (const float*)d_in[10];
  float* out = (float*)d_out;

  lstm_fwd_kernel<<<BB / CHUNK, 256, 0, stream>>>(X, Wih_f, Whh_f, bih_f, bhh_f, Wfc, out);
  lstm_bwd_fc_kernel<<<BB, 256, 0, stream>>>(X, Wih_b, bih_b, bhh_b, Wfc, bfc, out);
}

// Round 2
// 378.317 us; speedup vs baseline: 1.0211x; 1.0211x over previous
//
#include <hip/hip_runtime.h>

typedef __attribute__((ext_vector_type(8))) short bf16x8;
typedef __attribute__((ext_vector_type(4))) float f32x4;

#define BB 1024
#define TT 256
#define DD 63
#define HH 128
#define CHUNK 4
#define HSTR 136   // hbuf row stride in shorts (rows 0..3 only)
#define XSTR 72    // xbuf row stride in shorts

__device__ __forceinline__ short f2bf(float f) {
  unsigned u = __builtin_bit_cast(unsigned, f);
  u = (u + 0x7FFFu + ((u >> 16) & 1u)) >> 16;   // RNE
  return (short)u;
}
__device__ __forceinline__ float sigm(float x) {
  return __builtin_amdgcn_rcpf(1.f + __expf(-x));
}
__device__ __forceinline__ float tanh_fast(float x) {
  float e = __expf(2.f * x);
  return 1.f - 2.f * __builtin_amdgcn_rcpf(e + 1.f);
}

// 512 threads = 8 waves = 2 waves/SIMD. Wave w: gate g=w>>1, column half w&1.
// Each wave: 4 n-tiles (16x16x32 MFMA), B-frags register-resident (96 VGPR).
__global__ __launch_bounds__(512, 2)
void lstm_fwd_kernel(const float* __restrict__ X,
                     const float* __restrict__ Wih,
                     const float* __restrict__ Whh,
                     const float* __restrict__ bih,
                     const float* __restrict__ bhh,
                     const float* __restrict__ Wfc,
                     float* __restrict__ out) {
  __shared__ __align__(16) short hbuf[4 * HSTR];          // h (bf16), rows 0..3
  __shared__ __align__(16) short xbuf[2 * 4 * XSTR];      // x_t (bf16), 2 slots
  __shared__ __align__(16) float gl[512 * 4];             // gates, row-swizzled

  const int tid  = threadIdx.x;
  const int wave = tid >> 6;
  const int lane = tid & 63;
  const int quad = lane >> 4;
  const int l15  = lane & 15;
  const int b0   = blockIdx.x * CHUNK;
  const int g    = wave >> 1;
  const int half = wave & 1;
  const bool hib = (l15 >> 3) != 0;

  // ---- register-resident W fragments ----
  bf16x8 Bh[4][4];   // W_hh: tile, kstep(32)
  bf16x8 Bx[4][2];   // W_ih: tile, kstep(32), K padded 63->64
#pragma unroll
  for (int tile = 0; tile < 4; ++tile) {
    const int n = g * 128 + half * 64 + tile * 16 + l15;
    const float* wr = Whh + (size_t)n * HH;
#pragma unroll
    for (int ks = 0; ks < 4; ++ks) {
      const int k0 = ks * 32 + quad * 8;
      f32x4 w0 = *(const f32x4*)(wr + k0);
      f32x4 w1 = *(const f32x4*)(wr + k0 + 4);
      bf16x8 v;
#pragma unroll
      for (int jj = 0; jj < 4; ++jj) { v[jj] = f2bf(w0[jj]); v[4 + jj] = f2bf(w1[jj]); }
      Bh[tile][ks] = v;
    }
    const float* xr = Wih + (size_t)n * DD;
#pragma unroll
    for (int ks = 0; ks < 2; ++ks) {
      const int k0 = ks * 32 + quad * 8;
      bf16x8 v;
#pragma unroll
      for (int jj = 0; jj < 8; ++jj) {
        const int k = k0 + jj;
        v[jj] = (k < DD) ? f2bf(xr[k]) : (short)0;
      }
      Bx[tile][ks] = v;
    }
  }

  // elementwise mapping: 1 element per thread — col j, row r
  const int j = tid & 127;
  const int r = tid >> 7;
  const int s = (r + (j >> 3)) & 3;   // swizzle slot for gate reads
  float bg[4];
#pragma unroll
  for (int gg = 0; gg < 4; ++gg) bg[gg] = bih[gg * HH + j] + bhh[gg * HH + j];

  for (int i = tid; i < 4 * HSTR; i += 512) hbuf[i] = 0;

  // x prefetch: 4 rows x 63 cols = 252 threads; distance-2 pipeline
  const int xrow = tid / DD;
  const int xd   = tid - xrow * DD;
  const bool xthr = (tid < CHUNK * DD);
  const float* xbase = X + ((size_t)(b0 + xrow) * TT) * DD + xd;
  float xv_pend = 0.f;
  if (xthr) {
    xbuf[xrow * XSTR + xd] = f2bf(xbase[0]);   // slot 0 = x(0)
    xv_pend = xbase[DD];                        // x(1), stored at end of t=0
  }
  __syncthreads();

  float cc = 0.f, hv = 0.f;
  const f32x4 zero4 = {0.f, 0.f, 0.f, 0.f};

  for (int t = 0; t < TT; ++t) {
    const int cur = (t & 1) * (4 * XSTR);

    // issue next-next x load early (covered by ~1.5 steps)
    float xv_new = 0.f;
    const bool pf2 = xthr && (t + 2 < TT);
    if (pf2) xv_new = xbase[(size_t)(t + 2) * DD];

    // A-fragments: rows via l15&3 -> 4-way same-address broadcast (1/4 LDS BW)
    bf16x8 Ah[4], Ax[2];
#pragma unroll
    for (int ks = 0; ks < 4; ++ks)
      Ah[ks] = *(const bf16x8*)&hbuf[(l15 & 3) * HSTR + ks * 32 + quad * 8];
#pragma unroll
    for (int ks = 0; ks < 2; ++ks)
      Ax[ks] = *(const bf16x8*)&xbuf[cur + (l15 & 3) * XSTR + ks * 32 + quad * 8];

    // ---- MFMA: gates = h @ Whh^T + x @ Wih^T ----
    f32x4 acc[4];
#pragma unroll
    for (int tile = 0; tile < 4; ++tile)
      acc[tile] = __builtin_amdgcn_mfma_f32_16x16x32_bf16(Ah[0], Bh[tile][0], zero4, 0, 0, 0);
#pragma unroll
    for (int ks = 1; ks < 4; ++ks)
#pragma unroll
      for (int tile = 0; tile < 4; ++tile)
        acc[tile] = __builtin_amdgcn_mfma_f32_16x16x32_bf16(Ah[ks], Bh[tile][ks], acc[tile], 0, 0, 0);
#pragma unroll
    for (int ks = 0; ks < 2; ++ks)
#pragma unroll
      for (int tile = 0; tile < 4; ++tile)
        acc[tile] = __builtin_amdgcn_mfma_f32_16x16x32_bf16(Ax[ks], Bx[tile][ks], acc[tile], 0, 0, 0);

    // ---- gate write: b128 at n*4 with rows rotated by (n>>3)&3 ----
    // writer: component d holds row (d - rot)&3  <->  reader slot s=(r+(n>>3))&3
    if (quad == 0) {
#pragma unroll
      for (int tile = 0; tile < 4; ++tile) {
        const int n = g * 128 + half * 64 + tile * 16 + l15;
        const int rb = (tile * 2) & 3;          // static part of rot
        f32x4 a = acc[tile];
        f32x4 ts;
        ts[0] = a[(4 - rb) & 3];
        ts[1] = a[(5 - rb) & 3];
        ts[2] = a[(6 - rb) & 3];
        ts[3] = a[(7 - rb) & 3];
        f32x4 o;                                 // dynamic rotate by hib
        o[0] = hib ? ts[3] : ts[0];
        o[1] = hib ? ts[0] : ts[1];
        o[2] = hib ? ts[1] : ts[2];
        o[3] = hib ? ts[2] : ts[3];
        *(f32x4*)&gl[(size_t)n * 4] = o;
      }
    }
    __syncthreads();

    // ---- elementwise: 1 element per thread, conflict-free swizzled reads ----
    const float vi = gl[0 * 512 + 4 * j + s];
    const float vf = gl[1 * 512 + 4 * j + s];
    const float vg = gl[2 * 512 + 4 * j + s];
    const float vo = gl[3 * 512 + 4 * j + s];
    {
      const float iv = sigm(vi + bg[0]);
      const float fv = sigm(vf + bg[1]);
      const float gv = tanh_fast(vg + bg[2]);
      const float ov = sigm(vo + bg[3]);
      cc = fv * cc + iv * gv;
      hv = ov * tanh_fast(cc);
      hbuf[r * HSTR + j] = f2bf(hv);
    }

    if (xthr && (t + 1 < TT))
      xbuf[(cur ^ (4 * XSTR)) + xrow * XSTR + xd] = f2bf(xv_pend);
    xv_pend = xv_new;
    __syncthreads();
  }

  // ---- epilogue: forward half of FC (fp32, no bias) ----
  gl[r * HH + j] = hv;   // stage h_f(T-1) as fp32 [4][128]
  __syncthreads();
  if (tid < 4 * 14) {
    const int rr = tid / 14, o = tid - rr * 14;
    const float* wr = Wfc + (size_t)o * (2 * HH);
    float acc = 0.f;
#pragma unroll 16
    for (int k = 0; k < HH; ++k) acc += wr[k] * gl[rr * HH + k];
    out[(size_t)(b0 + rr) * 14 + o] = acc;
  }
}

// Backward direction collapses to ONE cell step on x[:,T-1] (h0=c0=0),
// done in exact fp32, plus the backward half of the FC (+ biases).
__global__ __launch_bounds__(256, 2)
void lstm_bwd_fc_kernel(const float* __restrict__ X,
                        const float* __restrict__ Wih_b,
                        const float* __restrict__ bih_b,
                        const float* __restrict__ bhh_b,
                        const float* __restrict__ Wfc,
                        const float* __restrict__ bfc,
                        float* __restrict__ out) {
  __shared__ float xl[DD];
  __shared__ float glb[4 * HH];
  __shared__ float hl[HH];
  __shared__ float pl[14 * 8];
  const int b = blockIdx.x;
  const int tid = threadIdx.x;

  if (tid < DD) xl[tid] = X[((size_t)b * TT + (TT - 1)) * DD + tid];
  __syncthreads();

#pragma unroll
  for (int u = 0; u < 2; ++u) {
    const int n = tid * 2 + u;
    const float* wr = Wih_b + (size_t)n * DD;
    float acc = bih_b[n] + bhh_b[n];
#pragma unroll
    for (int k = 0; k < DD; ++k) acc += wr[k] * xl[k];
    glb[n] = acc;
  }
  __syncthreads();

  if (tid < HH) {
    float iv = sigm(glb[0 * HH + tid]);
    float gv = tanh_fast(glb[2 * HH + tid]);
    float ov = sigm(glb[3 * HH + tid]);
    hl[tid] = ov * tanh_fast(iv * gv);   // c = f*0 + i*g
  }
  __syncthreads();

  if (tid < 14 * 8) {
    const int o = tid >> 3, kp = tid & 7;
    const float* wr = Wfc + (size_t)o * (2 * HH) + HH;
    float acc = 0.f;
#pragma unroll
    for (int i = 0; i < 16; ++i) {
      const int jj = kp * 16 + i;
      acc += wr[jj] * hl[jj];
    }
    pl[tid] = acc;
  }
  __syncthreads();

  if (tid < 14) {
    float acc = bfc[tid];
#pragma unroll
    for (int i = 0; i < 8; ++i) acc += pl[tid * 8 + i];
    out[(size_t)b * 14 + tid] += acc;   // add to forward partial
  }
}

extern "C" void kernel_launch(void* const* d_in, const int* in_sizes, int n_in,
                              void* d_out, int out_size, void* d_ws, size_t ws_size,
                              hipStream_t stream) {
  const float* X     = (const float*)d_in[0];
  const float* Wih_f = (const float*)d_in[1];
  const float* Whh_f = (const float*)d_in[2];
  const float* bih_f = (const float*)d_in[3];
  const float* bhh_f = (const float*)d_in[4];
  const float* Wih_b = (const float*)d_in[5];
  // d_in[6] = W_hh_b: unused (backward dir needs only one step from zero state)
  const float* bih_b = (const float*)d_in[7];
  const float* bhh_b = (const float*)d_in[8];
  const float* Wfc   = (const float*)d_in[9];
  const float* bfc   = (const float*)d_in[10];
  float* out = (float*)d_out;

  lstm_fwd_kernel<<<BB / CHUNK, 512, 0, stream>>>(X, Wih_f, Whh_f, bih_f, bhh_f, Wfc, out);
  lstm_bwd_fc_kernel<<<BB, 256, 0, stream>>>(X, Wih_b, bih_b, bhh_b, Wfc, bfc, out);
}